// Round 11
// baseline (356.953 us; speedup 1.0000x reference)
//
#include <hip/hip_runtime.h>
#include <cstdint>
#include <cstddef>

// Instant-NGP multires hash encoding, MI355X.
//
// Round-8 kernel, fourth submission (rounds 8-10 hit GPU-acquisition
// timeouts; never executed): round-5 structure (PPT=1, time-phased levels,
// x-pair merged 16B gathers, LDS transpose) + L1-BYPASS (sc0) on the 4
// merged block loads, implemented as ONE asm block: 4x buffer_load_dwordx4
// sc0 + s_waitcnt vmcnt(0) inside the same asm. Round-7's failure mode
// (separate load asm statements + separate waitcnt -> compiler-inserted
// register copies between load issue and data arrival) is structurally
// impossible here: the data is resident before the asm block's outputs
// become visible to the compiler. "=&v" early-clobber prevents
// output/input aliasing. Unmerged c-corner loads (~2/point avg) remain
// plain HIP loads (compiler-tracked).

typedef float f32x2 __attribute__((ext_vector_type(2)));
typedef float f32x4 __attribute__((ext_vector_type(4)));
typedef uint32_t u32x4 __attribute__((ext_vector_type(4)));

#define NUM_LEVELS 16
#define BLOCK 256

__global__ __launch_bounds__(BLOCK) void hashenc_gather(
    const float* __restrict__ x,
    const float* __restrict__ table,
    const float* __restrict__ scalings,
    const int* __restrict__ hash_offset,
    const int* __restrict__ tsp,
    float* __restrict__ ws,           // [L][N] f32x2, level-major
    int n_points, int bpl)            // bpl = blocks per level
{
    // Big/small alternation so slot-boundary straddles co-residence a 4MB
    // slab with a small one.
    static const int perm_arr[NUM_LEVELS] =
        {15, 0, 14, 1, 13, 2, 12, 3, 11, 4, 10, 9, 8, 7, 6, 5};

    const int bid   = (int)blockIdx.x;
    const int slot  = bid / bpl;                    // wave-uniform
    const int level = perm_arr[slot];
    const int n     = (bid - slot * bpl) * BLOCK + (int)threadIdx.x;
    if (n >= n_points) return;

    const float    s    = scalings[level];
    const int      off  = hash_offset[level];
    const uint32_t ts   = (uint32_t)tsp[0];
    const bool     pow2 = (ts & (ts - 1u)) == 0u;   // uniform branch
    const uint32_t mask = ts - 1u;

    const float px = x[n * 3 + 0];
    const float py = x[n * 3 + 1];
    const float pz = x[n * 3 + 2];

    const float sx = px * s, sy = py * s, sz = pz * s;
    const float fxf = floorf(sx), fyf = floorf(sy), fzf = floorf(sz);
    const float tx = sx - fxf, ty = sy - fyf, tz = sz - fzf;

    const uint32_t fxi = (uint32_t)(int)fxf;
    const uint32_t fyi = (uint32_t)(int)fyf;
    const uint32_t fzi = (uint32_t)(int)fzf;
    const uint32_t cxi = (uint32_t)(int)ceilf(sx);
    const uint32_t cyi = (uint32_t)(int)ceilf(sy);
    const uint32_t czi = (uint32_t)(int)ceilf(sz);

    const uint32_t P1 = 2654435761u, P2 = 805459861u;
    const uint32_t hyf = fyi * P1, hyc = cyi * P1;
    const uint32_t hzf = fzi * P2, hzc = czi * P2;

    // y/z hash parts; per part, two x-corners (c uses cxi, f uses fxi).
    const uint32_t A[4] = {hyc ^ hzc, hyc ^ hzf, hyf ^ hzc, hyf ^ hzf};

    const float ux = 1.f - tx, uy = 1.f - ty, uz = 1.f - tz;
    // Weight pairs (wc = ceil-x corner, wf = floor-x corner), reference order.
    float wc[4], wf[4];
    wc[0] = tx * ty * tz;  wf[0] = ux * ty * tz;   // v0 / v3
    wc[1] = tx * uy * tz;  wf[1] = tx * uy * uz;   // v1 / v5
    wc[2] = ux * uy * tz;  wf[2] = ux * uy * uz;   // v2 / v6
    wc[3] = tx * ty * uz;  wf[3] = ux * ty * uz;   // v4 / v7

    f32x2 acc = {0.f, 0.f};
    f32x2* wsl = reinterpret_cast<f32x2*>(ws) + (size_t)level * n_points;

    if (pow2) {
        uint32_t hf[4], hc[4], bf[4];
        bool mg[4];
#pragma unroll
        for (int j = 0; j < 4; ++j) {
            hf[j] = (fxi ^ A[j]) & mask;
            hc[j] = (cxi ^ A[j]) & mask;
            bf[j] = hf[j] >> 1;
            mg[j] = (hc[j] >> 1) == bf[j];
        }

        // Exec-masked 8B loads for unmerged c-corners (~50% of lanes),
        // plain HIP loads (compiler-tracked), issued before the asm block
        // so they overlap the sc0 loads' latency.
        const f32x2* tb2 = reinterpret_cast<const f32x2*>(table) + off;
        f32x2 el[4];
#pragma unroll
        for (int j = 0; j < 4; ++j) {
            el[j].x = 0.f; el[j].y = 0.f;
            if (!mg[j]) el[j] = tb2[hc[j]];
        }

        // SRD for this level's slab (uniform -> SGPR quad).
        const uint64_t base = (uint64_t)(const void*)(table + (size_t)off * 2);
        u32x4 srd;
        srd.x = (uint32_t)base;
        srd.y = (uint32_t)(base >> 32);
        srd.z = ts * 8u;            // num_records in bytes (stride==0)
        srd.w = 0x00020000u;        // raw dword access

        // 4 merged 16B block loads, L1-bypassed (sc0), single asm block with
        // the vmcnt drain INSIDE: outputs are physically resident before the
        // compiler sees them defined. "=&v": no aliasing with voffset inputs.
        f32x4 q0, q1, q2, q3;
        asm volatile(
            "buffer_load_dwordx4 %0, %4, %8, 0 offen sc0\n\t"
            "buffer_load_dwordx4 %1, %5, %8, 0 offen sc0\n\t"
            "buffer_load_dwordx4 %2, %6, %8, 0 offen sc0\n\t"
            "buffer_load_dwordx4 %3, %7, %8, 0 offen sc0\n\t"
            "s_waitcnt vmcnt(0)"
            : "=&v"(q0), "=&v"(q1), "=&v"(q2), "=&v"(q3)
            : "v"(bf[0] * 16u), "v"(bf[1] * 16u),
              "v"(bf[2] * 16u), "v"(bf[3] * 16u),
              "s"(srd)
            : "memory");
        __builtin_amdgcn_sched_barrier(0);

        const f32x4 q[4] = {q0, q1, q2, q3};
#pragma unroll
        for (int j = 0; j < 4; ++j) {
            const f32x2 qlo = {q[j].x, q[j].y};
            const f32x2 qhi = {q[j].z, q[j].w};
            const f32x2 ef = (hf[j] & 1u) ? qhi : qlo;
            const f32x2 eh = (hc[j] & 1u) ? qhi : qlo;
            const f32x2 ec = mg[j] ? eh : el[j];
            acc.x = fmaf(wf[j], ef.x, acc.x);
            acc.y = fmaf(wf[j], ef.y, acc.y);
            acc.x = fmaf(wc[j], ec.x, acc.x);
            acc.y = fmaf(wc[j], ec.y, acc.y);
        }
    } else {
        // Generic path (non-pow2 table): plain 8 gathers.
        const f32x2* tb2 = reinterpret_cast<const f32x2*>(table) + off;
        uint32_t h[8];
        h[0] = (cxi ^ A[0]) % ts; h[3] = (fxi ^ A[0]) % ts;
        h[1] = (cxi ^ A[1]) % ts; h[5] = (fxi ^ A[1]) % ts;
        h[2] = (cxi ^ A[2]) % ts; h[6] = (fxi ^ A[2]) % ts;
        h[4] = (cxi ^ A[3]) % ts; h[7] = (fxi ^ A[3]) % ts;
        f32x2 f[8];
#pragma unroll
        for (int c = 0; c < 8; ++c) f[c] = tb2[h[c]];
        const float w[8] = {wc[0], wc[1], wc[2], wf[0], wc[3], wf[1], wf[2], wf[3]};
#pragma unroll
        for (int c = 0; c < 8; ++c) {
            acc.x = fmaf(w[c], f[c].x, acc.x);
            acc.y = fmaf(w[c], f[c].y, acc.y);
        }
    }

    // nt store: don't let the 67MB ws stream evict the L2-resident slab.
    __builtin_nontemporal_store(acc, wsl + n);
}

// ws [L][N] f32x2 -> out [N][L] f32x2 via LDS tile.
__global__ __launch_bounds__(BLOCK) void hashenc_transpose(
    const float* __restrict__ ws, float* __restrict__ out, int n_points)
{
    __shared__ f32x2 tile[NUM_LEVELS][BLOCK + 2];

    const int base = (int)blockIdx.x * BLOCK;
    const int t    = (int)threadIdx.x;
    const int n    = base + t;
    const bool full = (base + BLOCK) <= n_points;

    if (full) {
#pragma unroll
        for (int l = 0; l < NUM_LEVELS; ++l)
            tile[l][t] = __builtin_nontemporal_load(
                reinterpret_cast<const f32x2*>(ws) + (size_t)l * n_points + n);
        __syncthreads();

        const int p0 = t >> 3;
        const int j  = t & 7;
        f32x4* o = reinterpret_cast<f32x4*>(out + (size_t)base * (NUM_LEVELS * 2));
#pragma unroll
        for (int i = 0; i < 8; ++i) {
            const int p = i * 32 + p0;
            const f32x2 a = tile[2 * j][p];
            const f32x2 b = tile[2 * j + 1][p];
            f32x4 v;
            v.x = a.x; v.y = a.y; v.z = b.x; v.w = b.y;
            __builtin_nontemporal_store(v, o + i * BLOCK + t);
        }
    } else if (n < n_points) {
        f32x2 v[NUM_LEVELS];
#pragma unroll
        for (int l = 0; l < NUM_LEVELS; ++l)
            v[l] = reinterpret_cast<const f32x2*>(ws)[(size_t)l * n_points + n];
        f32x4* o = reinterpret_cast<f32x4*>(out + (size_t)n * (NUM_LEVELS * 2));
#pragma unroll
        for (int i = 0; i < 8; ++i) {
            f32x4 w;
            w.x = v[2*i].x;   w.y = v[2*i].y;
            w.z = v[2*i+1].x; w.w = v[2*i+1].y;
            __builtin_nontemporal_store(w, o + i);
        }
    }
}

// Fallback (ws too small): direct strided store.
__global__ __launch_bounds__(BLOCK) void hashenc_direct(
    const float* __restrict__ x,
    const float* __restrict__ table,
    const float* __restrict__ scalings,
    const int* __restrict__ hash_offset,
    const int* __restrict__ tsp,
    float* __restrict__ out,
    int n_points)
{
    const int tid = blockIdx.x * BLOCK + (int)threadIdx.x;
    if (tid >= n_points * NUM_LEVELS) return;
    const int n = tid >> 4, l = tid & 15;

    const float s = scalings[l];
    const int off = hash_offset[l];
    const uint32_t ts = (uint32_t)tsp[0];
    const bool pow2 = (ts & (ts - 1u)) == 0u;
    const uint32_t mask = ts - 1u;

    const float sx = x[n*3]*s, sy = x[n*3+1]*s, sz = x[n*3+2]*s;
    const float fxf = floorf(sx), fyf = floorf(sy), fzf = floorf(sz);
    const float tx = sx - fxf, ty = sy - fyf, tz = sz - fzf;
    const uint32_t fxi = (uint32_t)(int)fxf, fyi = (uint32_t)(int)fyf, fzi = (uint32_t)(int)fzf;
    const uint32_t cxi = (uint32_t)(int)ceilf(sx), cyi = (uint32_t)(int)ceilf(sy), czi = (uint32_t)(int)ceilf(sz);
    const uint32_t P1 = 2654435761u, P2 = 805459861u;
    const uint32_t hyf = fyi*P1, hyc = cyi*P1, hzf = fzi*P2, hzc = czi*P2;
    uint32_t h[8] = {cxi^hyc^hzc, cxi^hyc^hzf, cxi^hyf^hzc, fxi^hyc^hzc,
                     cxi^hyf^hzf, fxi^hyc^hzf, fxi^hyf^hzc, fxi^hyf^hzf};
    const f32x2* tb = reinterpret_cast<const f32x2*>(table) + off;
    f32x2 f[8];
#pragma unroll
    for (int c = 0; c < 8; ++c) f[c] = tb[pow2 ? (h[c] & mask) : (h[c] % ts)];
    const float ux = 1.f-tx, uy = 1.f-ty, uz = 1.f-tz;
    float w[8] = {tx*ty*tz, tx*uy*tz, ux*uy*tz, ux*ty*tz,
                  tx*ty*uz, tx*uy*uz, ux*uy*uz, ux*ty*uz};
    f32x2 acc = {0.f, 0.f};
#pragma unroll
    for (int c = 0; c < 8; ++c) {
        acc.x = fmaf(w[c], f[c].x, acc.x);
        acc.y = fmaf(w[c], f[c].y, acc.y);
    }
    __builtin_nontemporal_store(acc, reinterpret_cast<f32x2*>(out) + tid);
}

extern "C" void kernel_launch(void* const* d_in, const int* in_sizes, int n_in,
                              void* d_out, int out_size, void* d_ws, size_t ws_size,
                              hipStream_t stream) {
    const float* x           = (const float*)d_in[0];
    const float* hash_table  = (const float*)d_in[1];
    const float* scalings    = (const float*)d_in[2];
    const int*   hash_offset = (const int*)d_in[3];
    const int*   table_size  = (const int*)d_in[4];
    float*       out         = (float*)d_out;

    const int n_points = in_sizes[0] / 3;
    const int bpl      = (n_points + BLOCK - 1) / BLOCK;   // blocks per level
    const size_t ws_needed = (size_t)n_points * NUM_LEVELS * 2 * sizeof(float);

    if (ws_size >= ws_needed) {
        hashenc_gather<<<NUM_LEVELS * bpl, BLOCK, 0, stream>>>(
            x, hash_table, scalings, hash_offset, table_size,
            (float*)d_ws, n_points, bpl);
        hashenc_transpose<<<bpl, BLOCK, 0, stream>>>(
            (const float*)d_ws, out, n_points);
    } else {
        const int total = n_points * NUM_LEVELS;
        hashenc_direct<<<(total + BLOCK - 1) / BLOCK, BLOCK, 0, stream>>>(
            x, hash_table, scalings, hash_offset, table_size, out, n_points);
    }
}